// Round 1
// baseline (886.364 us; speedup 1.0000x reference)
//
#include <hip/hip_runtime.h>
#include <cmath>

#define C_  192
#define HH  56
#define WW  56
#define NN  (HH*WW)      // 3136
#define BB  8
#define MH  28
#define MW  28
#define MM  (MH*MW)      // 784
#define NHEAD 4
#define HD  48
#define QT  32
#define KT  64
#define NTILES ((MM + KT - 1)/KT)   // 13

// ---------------------------------------------------------------------------
// Fold pointwise-conv into projection:  M[o][i] = sum_j W[o][j] * P[j][i]
// grid = C_ (one block per output row o), block = C_ threads (one per col i)
__global__ __launch_bounds__(C_) void combine_kernel(
    const float* __restrict__ Wmat, const float* __restrict__ P,
    float* __restrict__ Mout)
{
    int o = blockIdx.x;
    int c = threadIdx.x;
    __shared__ float wrow[C_];
    wrow[c] = Wmat[o*C_ + c];
    __syncthreads();
    float acc = 0.f;
    #pragma unroll 8
    for (int j = 0; j < C_; ++j)
        acc = fmaf(wrow[j], P[j*C_ + c], acc);
    Mout[o*C_ + c] = acc;
}

// ---------------------------------------------------------------------------
// Depthwise 3x3 conv (pad 1) + BN, channel-last, float4 over channels.
// out layout: (B, OH*OW, C)
__global__ __launch_bounds__(256) void dwbn_kernel(
    const float* __restrict__ x, const float* __restrict__ dw,
    const float* __restrict__ gamma, const float* __restrict__ beta,
    const float* __restrict__ mean,  const float* __restrict__ var,
    float* __restrict__ out, int OH, int OW, int stride)
{
    int idx = blockIdx.x * blockDim.x + threadIdx.x;
    int total = BB*OH*OW*(C_/4);
    if (idx >= total) return;
    int c4 = idx % (C_/4);
    int sp = idx / (C_/4);
    int ox = sp % OW;
    int t2 = sp / OW;
    int oy = t2 % OH;
    int b  = t2 / OH;
    int c0 = c4*4;
    float4 acc = make_float4(0.f,0.f,0.f,0.f);
    int iy0 = oy*stride - 1;
    int ix0 = ox*stride - 1;
    #pragma unroll
    for (int ky = 0; ky < 3; ++ky) {
        int iy = iy0 + ky;
        if (iy < 0 || iy >= HH) continue;
        #pragma unroll
        for (int kx = 0; kx < 3; ++kx) {
            int ix = ix0 + kx;
            if (ix < 0 || ix >= WW) continue;
            float4 xv = *reinterpret_cast<const float4*>(
                x + ((size_t)b*NN + iy*WW + ix)*C_ + c0);
            int wi = ky*3 + kx;
            acc.x = fmaf(dw[(c0+0)*9 + wi], xv.x, acc.x);
            acc.y = fmaf(dw[(c0+1)*9 + wi], xv.y, acc.y);
            acc.z = fmaf(dw[(c0+2)*9 + wi], xv.z, acc.z);
            acc.w = fmaf(dw[(c0+3)*9 + wi], xv.w, acc.w);
        }
    }
    float4 r;
    {
        float inv = gamma[c0+0] / sqrtf(var[c0+0] + 1e-5f);
        r.x = acc.x*inv + (beta[c0+0] - mean[c0+0]*inv);
        inv = gamma[c0+1] / sqrtf(var[c0+1] + 1e-5f);
        r.y = acc.y*inv + (beta[c0+1] - mean[c0+1]*inv);
        inv = gamma[c0+2] / sqrtf(var[c0+2] + 1e-5f);
        r.z = acc.z*inv + (beta[c0+2] - mean[c0+2]*inv);
        inv = gamma[c0+3] / sqrtf(var[c0+3] + 1e-5f);
        r.w = acc.w*inv + (beta[c0+3] - mean[c0+3]*inv);
    }
    reinterpret_cast<float4*>(out)[idx] = r;
}

// ---------------------------------------------------------------------------
// Projection GEMM: out[r][o] = sum_c U[r][c]*Mmat[o][c] + bias[o]
// block = 192 threads (one output column each), 16 rows per block.
__global__ __launch_bounds__(C_) void proj_kernel(
    const float* __restrict__ U, const float* __restrict__ Mmat,
    const float* __restrict__ bias, float* __restrict__ out)
{
    __shared__ float uL[16][C_];
    int r0 = blockIdx.x * 16;
    int o  = threadIdx.x;
    #pragma unroll
    for (int r = 0; r < 16; ++r)
        uL[r][o] = U[(size_t)(r0 + r)*C_ + o];
    __syncthreads();
    float acc[16];
    float bvv = bias[o];
    #pragma unroll
    for (int r = 0; r < 16; ++r) acc[r] = bvv;
    const float* Mrow = Mmat + (size_t)o*C_;
    for (int c = 0; c < C_; c += 4) {
        float m0 = Mrow[c+0], m1 = Mrow[c+1], m2 = Mrow[c+2], m3 = Mrow[c+3];
        #pragma unroll
        for (int r = 0; r < 16; ++r) {
            acc[r] = fmaf(uL[r][c+0], m0, acc[r]);
            acc[r] = fmaf(uL[r][c+1], m1, acc[r]);
            acc[r] = fmaf(uL[r][c+2], m2, acc[r]);
            acc[r] = fmaf(uL[r][c+3], m3, acc[r]);
        }
    }
    #pragma unroll
    for (int r = 0; r < 16; ++r)
        out[(size_t)(r0 + r)*C_ + o] = acc[r];
}

// ---------------------------------------------------------------------------
// Flash attention, fp32. Block: 128 threads, 32 queries, 64-key tiles.
// qbuf/kbuf/vbuf layout: (B, N|M, C) with head h at columns [h*HD, (h+1)*HD).
// qbuf may alias out: block reads exactly the (rows, head-cols) it writes.
__global__ __launch_bounds__(128) void attn_kernel(
    const float* __restrict__ qbuf, const float* __restrict__ kbuf,
    const float* __restrict__ vbuf, float* __restrict__ out)
{
    __shared__ float qL[QT][52];
    __shared__ float kL[KT][52];
    __shared__ float vL[KT][52];
    __shared__ float sL[QT][66];
    __shared__ float mrun[QT], lrun[QT];

    int tid = threadIdx.x;
    int bid = blockIdx.x;
    int qt  = bid % (NN/QT);
    int h   = (bid/(NN/QT)) % NHEAD;
    int b   = bid/((NN/QT)*NHEAD);
    int n0  = qt*QT;

    const float scale = 0.14433756729740643f;   // 1/sqrt(48)

    // load Q tile (pre-scaled)
    for (int u = tid; u < QT*(HD/4); u += 128) {
        int r = u/(HD/4), d4 = u%(HD/4);
        float4 qv = *reinterpret_cast<const float4*>(
            qbuf + ((size_t)b*NN + n0 + r)*C_ + h*HD + d4*4);
        qv.x *= scale; qv.y *= scale; qv.z *= scale; qv.w *= scale;
        *reinterpret_cast<float4*>(&qL[r][d4*4]) = qv;
    }
    if (tid < QT) { mrun[tid] = -1e30f; lrun[tid] = 0.f; }

    int qg = tid >> 4;     // 0..7 : owns query rows qg*4 .. qg*4+3
    int kg = tid & 15;     // 0..15: owns keys kg + j*16 (scores phase)
    int d0 = (tid & 15)*3; // PV phase: 3 output dims

    float oacc[4][3];
    #pragma unroll
    for (int i = 0; i < 4; ++i)
        for (int d = 0; d < 3; ++d) oacc[i][d] = 0.f;

    for (int t = 0; t < NTILES; ++t) {
        int m0 = t*KT;
        // stage K/V tile
        for (int u = tid; u < KT*(HD/4); u += 128) {
            int r = u/(HD/4), d4 = u%(HD/4);
            int m = m0 + r;
            float4 kv = make_float4(0.f,0.f,0.f,0.f);
            float4 vv = make_float4(0.f,0.f,0.f,0.f);
            if (m < MM) {
                size_t base = ((size_t)b*MM + m)*C_ + h*HD + d4*4;
                kv = *reinterpret_cast<const float4*>(kbuf + base);
                vv = *reinterpret_cast<const float4*>(vbuf + base);
            }
            *reinterpret_cast<float4*>(&kL[r][d4*4]) = kv;
            *reinterpret_cast<float4*>(&vL[r][d4*4]) = vv;
        }
        __syncthreads();

        // scores: 4q x 4k micro-tile
        float s[4][4];
        #pragma unroll
        for (int i = 0; i < 4; ++i)
            for (int j = 0; j < 4; ++j) s[i][j] = 0.f;
        for (int d4 = 0; d4 < HD/4; ++d4) {
            float4 qv[4], kv[4];
            #pragma unroll
            for (int i = 0; i < 4; ++i)
                qv[i] = *reinterpret_cast<const float4*>(&qL[qg*4+i][d4*4]);
            #pragma unroll
            for (int j = 0; j < 4; ++j)
                kv[j] = *reinterpret_cast<const float4*>(&kL[kg + j*16][d4*4]);
            #pragma unroll
            for (int i = 0; i < 4; ++i)
                #pragma unroll
                for (int j = 0; j < 4; ++j) {
                    s[i][j] = fmaf(qv[i].x, kv[j].x, s[i][j]);
                    s[i][j] = fmaf(qv[i].y, kv[j].y, s[i][j]);
                    s[i][j] = fmaf(qv[i].z, kv[j].z, s[i][j]);
                    s[i][j] = fmaf(qv[i].w, kv[j].w, s[i][j]);
                }
        }
        // mask invalid keys (last tile)
        #pragma unroll
        for (int j = 0; j < 4; ++j) {
            int key = m0 + kg + j*16;
            if (key >= MM) {
                #pragma unroll
                for (int i = 0; i < 4; ++i) s[i][j] = -1e30f;
            }
        }
        // online softmax (width-16 shuffle reductions; 16 lanes share a row)
        float corr[4];
        #pragma unroll
        for (int i = 0; i < 4; ++i) {
            float tmax = fmaxf(fmaxf(s[i][0], s[i][1]), fmaxf(s[i][2], s[i][3]));
            #pragma unroll
            for (int off = 1; off < 16; off <<= 1)
                tmax = fmaxf(tmax, __shfl_xor(tmax, off));
            int row = qg*4 + i;
            float mold = mrun[row];
            float mnew = fmaxf(mold, tmax);
            corr[i] = __expf(mold - mnew);
            float psum = 0.f;
            #pragma unroll
            for (int j = 0; j < 4; ++j) {
                float p = __expf(s[i][j] - mnew);
                s[i][j] = p;
                psum += p;
            }
            #pragma unroll
            for (int off = 1; off < 16; off <<= 1)
                psum += __shfl_xor(psum, off);
            if (kg == 0) {
                lrun[row] = lrun[row]*corr[i] + psum;
                mrun[row] = mnew;
            }
            #pragma unroll
            for (int j = 0; j < 4; ++j)
                sL[row][kg + j*16] = s[i][j];
        }
        __syncthreads();

        // PV: 4q x 3d micro-tile
        #pragma unroll
        for (int i = 0; i < 4; ++i) {
            oacc[i][0] *= corr[i];
            oacc[i][1] *= corr[i];
            oacc[i][2] *= corr[i];
        }
        for (int kk = 0; kk < KT; ++kk) {
            float v0 = vL[kk][d0+0];
            float v1 = vL[kk][d0+1];
            float v2 = vL[kk][d0+2];
            #pragma unroll
            for (int i = 0; i < 4; ++i) {
                float p = sL[qg*4+i][kk];
                oacc[i][0] = fmaf(p, v0, oacc[i][0]);
                oacc[i][1] = fmaf(p, v1, oacc[i][1]);
                oacc[i][2] = fmaf(p, v2, oacc[i][2]);
            }
        }
        __syncthreads();
    }

    #pragma unroll
    for (int i = 0; i < 4; ++i) {
        int row = qg*4 + i;
        float invl = 1.f / lrun[row];
        size_t obase = ((size_t)b*NN + n0 + row)*C_ + h*HD + d0;
        out[obase+0] = oacc[i][0]*invl;
        out[obase+1] = oacc[i][1]*invl;
        out[obase+2] = oacc[i][2]*invl;
    }
}

// ---------------------------------------------------------------------------
extern "C" void kernel_launch(void* const* d_in, const int* in_sizes, int n_in,
                              void* d_out, int out_size, void* d_ws, size_t ws_size,
                              hipStream_t stream)
{
    const float* x     = (const float*)d_in[0];
    const float* dw_q  = (const float*)d_in[3];
    const float* bnqg  = (const float*)d_in[4];
    const float* bnqb  = (const float*)d_in[5];
    const float* bnqm  = (const float*)d_in[6];
    const float* bnqv  = (const float*)d_in[7];
    const float* pw_q  = (const float*)d_in[8];
    const float* dw_kv = (const float*)d_in[9];
    const float* bnkg  = (const float*)d_in[10];
    const float* bnkb  = (const float*)d_in[11];
    const float* bnkm  = (const float*)d_in[12];
    const float* bnkvv = (const float*)d_in[13];
    const float* pw_kv = (const float*)d_in[14];
    const float* Wq    = (const float*)d_in[15];
    const float* bq    = (const float*)d_in[16];
    const float* Wk    = (const float*)d_in[17];
    const float* bk    = (const float*)d_in[18];
    const float* Wv    = (const float*)d_in[19];
    const float* bv    = (const float*)d_in[20];
    float* out = (float*)d_out;

    float* ws  = (float*)d_ws;
    float* Mq  = ws;
    float* Mk  = Mq + C_*C_;
    float* Mv  = Mk + C_*C_;
    float* uq  = Mv + C_*C_;                  // B*N*C
    float* ukv = uq + (size_t)BB*NN*C_;       // B*M*C
    float* kb  = ukv + (size_t)BB*MM*C_;      // B*M*C
    float* vb  = kb  + (size_t)BB*MM*C_;      // B*M*C
    float* qb  = out;                         // q lives in d_out (safe: see attn)

    combine_kernel<<<C_, C_, 0, stream>>>(Wq, pw_q, Mq);
    combine_kernel<<<C_, C_, 0, stream>>>(Wk, pw_kv, Mk);
    combine_kernel<<<C_, C_, 0, stream>>>(Wv, pw_kv + C_*C_, Mv);

    int tot_q  = BB*NN*(C_/4);
    int tot_kv = BB*MM*(C_/4);
    dwbn_kernel<<<(tot_q  + 255)/256, 256, 0, stream>>>(
        x, dw_q,  bnqg, bnqb, bnqm, bnqv, uq,  HH, WW, 1);
    dwbn_kernel<<<(tot_kv + 255)/256, 256, 0, stream>>>(
        x, dw_kv, bnkg, bnkb, bnkm, bnkvv, ukv, MH, MW, 2);

    proj_kernel<<<BB*NN/16, C_, 0, stream>>>(uq,  Mq, bq, qb);
    proj_kernel<<<BB*MM/16, C_, 0, stream>>>(ukv, Mk, bk, kb);
    proj_kernel<<<BB*MM/16, C_, 0, stream>>>(ukv, Mv, bv, vb);

    attn_kernel<<<BB*NHEAD*(NN/QT), 128, 0, stream>>>(qb, kb, vb, out);
}

// Round 2
// 255.155 us; speedup vs baseline: 3.4738x; 3.4738x over previous
//
#include <hip/hip_runtime.h>
#include <cmath>

typedef _Float16 f16;
typedef _Float16 f16x8 __attribute__((ext_vector_type(8)));
typedef _Float16 f16x4 __attribute__((ext_vector_type(4)));
typedef float    f32x4 __attribute__((ext_vector_type(4)));

#define C_   192
#define HH   56
#define WW   56
#define NN   3136
#define BB   8
#define MM   784
#define NHEAD 4
#define HD   48
#define VT_LD 800        // padded key-dim of transposed V (784 + 16)

// ---------------------------------------------------------------------------
// Fold pointwise conv into projection: M[o][c] = sum_j W[o][j] * P[j][c], f16 out
__global__ __launch_bounds__(C_) void combine_f16(
    const float* __restrict__ Wmat, const float* __restrict__ P,
    f16* __restrict__ Mout)
{
    int o = blockIdx.x, c = threadIdx.x;
    __shared__ float wrow[C_];
    wrow[c] = Wmat[o*C_ + c];
    __syncthreads();
    float acc = 0.f;
    #pragma unroll 8
    for (int j = 0; j < C_; ++j)
        acc = fmaf(wrow[j], P[j*C_ + c], acc);
    Mout[o*C_ + c] = (f16)acc;
}

// ---------------------------------------------------------------------------
// Depthwise 3x3 + BN, channel-last, fp32 compute, f16 out
__global__ __launch_bounds__(256) void dwbn16_kernel(
    const float* __restrict__ x, const float* __restrict__ dw,
    const float* __restrict__ gamma, const float* __restrict__ beta,
    const float* __restrict__ mean,  const float* __restrict__ var,
    f16* __restrict__ out, int OH, int OW, int stride)
{
    int idx = blockIdx.x * blockDim.x + threadIdx.x;
    int total = BB*OH*OW*(C_/4);
    if (idx >= total) return;
    int c4 = idx % (C_/4);
    int sp = idx / (C_/4);
    int ox = sp % OW;
    int t2 = sp / OW;
    int oy = t2 % OH;
    int b  = t2 / OH;
    int c0 = c4*4;
    float4 acc = make_float4(0.f,0.f,0.f,0.f);
    int iy0 = oy*stride - 1;
    int ix0 = ox*stride - 1;
    #pragma unroll
    for (int ky = 0; ky < 3; ++ky) {
        int iy = iy0 + ky;
        if (iy < 0 || iy >= HH) continue;
        #pragma unroll
        for (int kx = 0; kx < 3; ++kx) {
            int ix = ix0 + kx;
            if (ix < 0 || ix >= WW) continue;
            float4 xv = *reinterpret_cast<const float4*>(
                x + ((size_t)b*NN + iy*WW + ix)*C_ + c0);
            int wi = ky*3 + kx;
            acc.x = fmaf(dw[(c0+0)*9 + wi], xv.x, acc.x);
            acc.y = fmaf(dw[(c0+1)*9 + wi], xv.y, acc.y);
            acc.z = fmaf(dw[(c0+2)*9 + wi], xv.z, acc.z);
            acc.w = fmaf(dw[(c0+3)*9 + wi], xv.w, acc.w);
        }
    }
    float i0 = gamma[c0+0]*__frsqrt_rn(var[c0+0] + 1e-5f);
    float i1 = gamma[c0+1]*__frsqrt_rn(var[c0+1] + 1e-5f);
    float i2 = gamma[c0+2]*__frsqrt_rn(var[c0+2] + 1e-5f);
    float i3 = gamma[c0+3]*__frsqrt_rn(var[c0+3] + 1e-5f);
    f16x4 r;
    r[0] = (f16)(acc.x*i0 + (beta[c0+0] - mean[c0+0]*i0));
    r[1] = (f16)(acc.y*i1 + (beta[c0+1] - mean[c0+1]*i1));
    r[2] = (f16)(acc.z*i2 + (beta[c0+2] - mean[c0+2]*i2));
    r[3] = (f16)(acc.w*i3 + (beta[c0+3] - mean[c0+3]*i3));
    *reinterpret_cast<f16x4*>(out + (size_t)idx*4) = r;
}

// ---------------------------------------------------------------------------
// Projection GEMM via MFMA: out[r][o] = (sum_c U[r][c]*M[o][c] + bias[o])*scale
// block = 256 (4 waves), each wave owns 16 rows; K = 192 = 6 chunks of 32.
// TRANS=1: write transposed into Vt[b][o][m] (rows are (b,m), 16-row tiles
// never cross a batch since 784 % 16 == 0).
template<int TRANS>
__global__ __launch_bounds__(256) void proj_mfma(
    const f16* __restrict__ U, const f16* __restrict__ Mmat,
    const float* __restrict__ bias, float scale,
    f16* __restrict__ out)
{
    int tid  = threadIdx.x;
    int w    = tid >> 6, l = tid & 63;
    int lrow = l & 15,  lgrp = l >> 4;
    int r0   = blockIdx.x*64 + w*16;

    const f16* urow = U + (size_t)(r0 + lrow)*C_;
    f16x8 a[6];
    #pragma unroll
    for (int ch = 0; ch < 6; ++ch)
        a[ch] = *(const f16x8*)(urow + ch*32 + lgrp*8);

    for (int ct = 0; ct < 12; ++ct) {
        int o = ct*16 + lrow;
        const f16* mrow = Mmat + (size_t)o*C_;
        f32x4 acc = {0.f,0.f,0.f,0.f};
        #pragma unroll
        for (int ch = 0; ch < 6; ++ch) {
            f16x8 bf = *(const f16x8*)(mrow + ch*32 + lgrp*8);
            acc = __builtin_amdgcn_mfma_f32_16x16x32_f16(a[ch], bf, acc, 0, 0, 0);
        }
        float bo = bias[o];
        if (TRANS == 0) {
            #pragma unroll
            for (int i = 0; i < 4; ++i) {
                int r = r0 + lgrp*4 + i;
                out[(size_t)r*C_ + o] = (f16)((acc[i] + bo)*scale);
            }
        } else {
            int rg = r0 + lgrp*4;
            int b  = rg / MM, m = rg % MM;
            #pragma unroll
            for (int i = 0; i < 4; ++i)
                out[((size_t)b*C_ + o)*VT_LD + m + i] = (f16)((acc[i] + bo)*scale);
        }
    }
}

// ---------------------------------------------------------------------------
// Zero-fill Vt pad columns m = 784..799 (so PV's masked tail reads finite zeros)
__global__ __launch_bounds__(256) void vt_pad(f16* __restrict__ vt)
{
    int i = blockIdx.x*256 + threadIdx.x;      // BB*192*16 = 24576
    if (i >= BB*C_*16) return;
    int b = i / (C_*16);
    int rem = i % (C_*16);
    int c = rem / 16;
    int m = MM + (rem & 15);
    vt[((size_t)b*C_ + c)*VT_LD + m] = (f16)0.f;
}

// ---------------------------------------------------------------------------
// Flash attention with MFMA. 4 waves x 16 q-rows = 64 q per block.
// KV tile = 112 keys (7 x 16, 784 = 7*112 exact, no masking).
// qb/kb: f16 [B][N|M][192] row-major; vt: f16 [B][192][800] (transposed V).
__global__ __launch_bounds__(256) void attn_mfma(
    const f16* __restrict__ qb, const f16* __restrict__ kb,
    const f16* __restrict__ vt, float* __restrict__ out)
{
    __shared__ __align__(16) f16 pL[4][16*128];   // per-wave P, XOR-swizzled

    int tid  = threadIdx.x;
    int w    = tid >> 6, l = tid & 63;
    int lrow = l & 15,  lgrp = l >> 4;
    int bid  = blockIdx.x;
    int qt   = bid % (NN/64);
    int h    = (bid/(NN/64)) & 3;
    int b    = bid / ((NN/64)*NHEAD);
    int n0   = qt*64 + w*16;
    f16* pw  = &pL[w][0];

    // zero the pad columns 112..127 once (never rewritten)
    {
        int q = lrow;
        int e = (q*128 + 112 + lgrp*4) ^ ((q & 7) << 3);
        *(f16x4*)(pw + e) = (f16x4){0,0,0,0};
    }

    // Q fragments (held in registers for the whole kernel); upper-d pad = 0
    const f16* qrow = qb + ((size_t)b*NN + n0 + lrow)*C_ + h*HD;
    f16x8 qf0 = *(const f16x8*)(qrow + lgrp*8);
    f16x8 qf1 = (f16x8){0,0,0,0,0,0,0,0};
    if (lgrp < 2) qf1 = *(const f16x8*)(qrow + 32 + lgrp*8);

    float mrun[4], lrun[4];
    #pragma unroll
    for (int r = 0; r < 4; ++r) { mrun[r] = -1e30f; lrun[r] = 0.f; }
    f32x4 o0 = {0.f,0.f,0.f,0.f}, o1 = o0, o2 = o0;

    for (int t = 0; t < 7; ++t) {
        int m0 = t*112;

        // ---- QK^T: S tile 16 x 112, K frags straight from global (L1/L2-hot)
        f32x4 s[7];
        #pragma unroll
        for (int kt = 0; kt < 7; ++kt) {
            const f16* krow = kb + ((size_t)b*MM + m0 + kt*16 + lrow)*C_ + h*HD;
            f16x8 kf0 = *(const f16x8*)(krow + lgrp*8);
            f16x8 kf1 = *(const f16x8*)(krow + 32 + lgrp*8); // d>=48 garbage*0=0
            f32x4 acc = {0.f,0.f,0.f,0.f};
            acc = __builtin_amdgcn_mfma_f32_16x16x32_f16(qf0, kf0, acc, 0, 0, 0);
            acc = __builtin_amdgcn_mfma_f32_16x16x32_f16(qf1, kf1, acc, 0, 0, 0);
            s[kt] = acc;
        }

        // ---- online softmax (fp32).  D row = lgrp*4+r, col = kt*16+lrow.
        float corr[4];
        #pragma unroll
        for (int r = 0; r < 4; ++r) {
            float tmax = s[0][r];
            #pragma unroll
            for (int kt = 1; kt < 7; ++kt) tmax = fmaxf(tmax, s[kt][r]);
            tmax = fmaxf(tmax, __shfl_xor(tmax, 1));
            tmax = fmaxf(tmax, __shfl_xor(tmax, 2));
            tmax = fmaxf(tmax, __shfl_xor(tmax, 4));
            tmax = fmaxf(tmax, __shfl_xor(tmax, 8));
            float mnew = fmaxf(mrun[r], tmax);
            corr[r] = __expf(mrun[r] - mnew);
            mrun[r] = mnew;
            float psum = 0.f;
            #pragma unroll
            for (int kt = 0; kt < 7; ++kt) {
                float p = __expf(s[kt][r] - mnew);
                s[kt][r] = p;
                psum += p;
            }
            psum += __shfl_xor(psum, 1);
            psum += __shfl_xor(psum, 2);
            psum += __shfl_xor(psum, 4);
            psum += __shfl_xor(psum, 8);
            lrun[r] = lrun[r]*corr[r] + psum;
        }

        // ---- write P (f16) to swizzled LDS
        #pragma unroll
        for (int r = 0; r < 4; ++r) {
            int q = lgrp*4 + r;
            #pragma unroll
            for (int kt = 0; kt < 7; ++kt) {
                int e = (q*128 + kt*16 + lrow) ^ ((q & 7) << 3);
                pw[e] = (f16)s[kt][r];
            }
        }
        __syncthreads();

        // ---- rescale O accumulators
        #pragma unroll
        for (int r = 0; r < 4; ++r) {
            o0[r] *= corr[r]; o1[r] *= corr[r]; o2[r] *= corr[r];
        }

        // ---- PV: O(16x48) += P(16x128) * V(128x48), V^T frags from global
        f16x8 pa[4];
        #pragma unroll
        for (int kc = 0; kc < 4; ++kc) {
            int e = (lrow*128 + kc*32 + lgrp*8) ^ ((lrow & 7) << 3);
            pa[kc] = *(const f16x8*)(pw + e);
        }
        const f16* vbase = vt + ((size_t)b*C_ + h*HD + lrow)*VT_LD + m0;
        #pragma unroll
        for (int kc = 0; kc < 4; ++kc) {
            f16x8 v0 = *(const f16x8*)(vbase + kc*32 + lgrp*8);
            f16x8 v1 = *(const f16x8*)(vbase + 16*VT_LD + kc*32 + lgrp*8);
            f16x8 v2 = *(const f16x8*)(vbase + 32*VT_LD + kc*32 + lgrp*8);
            o0 = __builtin_amdgcn_mfma_f32_16x16x32_f16(pa[kc], v0, o0, 0, 0, 0);
            o1 = __builtin_amdgcn_mfma_f32_16x16x32_f16(pa[kc], v1, o1, 0, 0, 0);
            o2 = __builtin_amdgcn_mfma_f32_16x16x32_f16(pa[kc], v2, o2, 0, 0, 0);
        }
        __syncthreads();   // protect pL before next tile's writes
    }

    // ---- epilogue: divide by l, store fp32
    #pragma unroll
    for (int r = 0; r < 4; ++r) {
        float inv = 1.f / lrun[r];
        size_t obase = ((size_t)b*NN + n0 + lgrp*4 + r)*C_ + h*HD + lrow;
        out[obase]      = o0[r]*inv;
        out[obase + 16] = o1[r]*inv;
        out[obase + 32] = o2[r]*inv;
    }
}

// ---------------------------------------------------------------------------
extern "C" void kernel_launch(void* const* d_in, const int* in_sizes, int n_in,
                              void* d_out, int out_size, void* d_ws, size_t ws_size,
                              hipStream_t stream)
{
    const float* x     = (const float*)d_in[0];
    const float* dw_q  = (const float*)d_in[3];
    const float* bnqg  = (const float*)d_in[4];
    const float* bnqb  = (const float*)d_in[5];
    const float* bnqm  = (const float*)d_in[6];
    const float* bnqv  = (const float*)d_in[7];
    const float* pw_q  = (const float*)d_in[8];
    const float* dw_kv = (const float*)d_in[9];
    const float* bnkg  = (const float*)d_in[10];
    const float* bnkb  = (const float*)d_in[11];
    const float* bnkm  = (const float*)d_in[12];
    const float* bnkvv = (const float*)d_in[13];
    const float* pw_kv = (const float*)d_in[14];
    const float* Wq    = (const float*)d_in[15];
    const float* bq    = (const float*)d_in[16];
    const float* Wk    = (const float*)d_in[17];
    const float* bk    = (const float*)d_in[18];
    const float* Wv    = (const float*)d_in[19];
    const float* bv    = (const float*)d_in[20];
    float* out = (float*)d_out;

    f16* p   = (f16*)d_ws;
    f16* Mq16  = p;  p += C_*C_;
    f16* Mk16  = p;  p += C_*C_;
    f16* Mv16  = p;  p += C_*C_;
    f16* uq16  = p;  p += (size_t)BB*NN*C_;
    f16* ukv16 = p;  p += (size_t)BB*MM*C_;
    f16* qb16  = p;  p += (size_t)BB*NN*C_ + 256;   // pad: frag tail reads
    f16* kb16  = p;  p += (size_t)BB*MM*C_ + 256;   // pad: frag tail reads
    f16* vt16  = p;  p += (size_t)BB*C_*VT_LD;

    combine_f16<<<C_, C_, 0, stream>>>(Wq, pw_q, Mq16);
    combine_f16<<<C_, C_, 0, stream>>>(Wk, pw_kv, Mk16);
    combine_f16<<<C_, C_, 0, stream>>>(Wv, pw_kv + C_*C_, Mv16);

    int tot_q  = BB*NN*(C_/4);
    int tot_kv = BB*MM*(C_/4);
    dwbn16_kernel<<<(tot_q  + 255)/256, 256, 0, stream>>>(
        x, dw_q,  bnqg, bnqb, bnqm, bnqv,  uq16,  HH, WW, 1);
    dwbn16_kernel<<<(tot_kv + 255)/256, 256, 0, stream>>>(
        x, dw_kv, bnkg, bnkb, bnkm, bnkvv, ukv16, MM/28, MM/28, 2);

    const float qscale = 0.14433756729740643f;   // 1/sqrt(48)
    proj_mfma<0><<<BB*NN/64, 256, 0, stream>>>(uq16,  Mq16, bq, qscale, qb16);
    proj_mfma<0><<<BB*MM/64, 256, 0, stream>>>(ukv16, Mk16, bk, 1.0f,   kb16);
    proj_mfma<1><<<BB*MM/64, 256, 0, stream>>>(ukv16, Mv16, bv, 1.0f,   vt16);
    vt_pad<<<(BB*C_*16 + 255)/256, 256, 0, stream>>>(vt16);

    attn_mfma<<<BB*NHEAD*(NN/64), 256, 0, stream>>>(qb16, kb16, vt16, out);
}

// Round 3
// 205.704 us; speedup vs baseline: 4.3089x; 1.2404x over previous
//
#include <hip/hip_runtime.h>
#include <cmath>

typedef _Float16 f16;
typedef _Float16 f16x8 __attribute__((ext_vector_type(8)));
typedef _Float16 f16x4 __attribute__((ext_vector_type(4)));
typedef float    f32x4 __attribute__((ext_vector_type(4)));

#define C_   192
#define HH   56
#define WW   56
#define NN   3136
#define BB   8
#define MM   784
#define NHEAD 4
#define HD   48
#define VT_LD 800            // padded key-dim of transposed V (784 + 16)
#define QPB  (BB*NN/64)      // 392 proj blocks, Q path
#define KVPB (BB*MM/64)      // 98 proj blocks, KV path

// ---------------------------------------------------------------------------
// Setup: blocks 0..575 = fold pointwise into projections (3 x 192 rows),
// blocks 576..703 = zero Vt pad columns m=784..799.  block = 192 threads.
__global__ __launch_bounds__(192) void setup_kernel(
    const float* __restrict__ Wq, const float* __restrict__ Wk,
    const float* __restrict__ Wv, const float* __restrict__ pw_q,
    const float* __restrict__ pw_kv,
    f16* __restrict__ Mq, f16* __restrict__ Mk, f16* __restrict__ Mv,
    f16* __restrict__ vt)
{
    int blk = blockIdx.x, tid = threadIdx.x;
    if (blk < 576) {
        int which = blk / 192, o = blk % 192;
        const float* Wm = which == 0 ? Wq : (which == 1 ? Wk : Wv);
        const float* P  = which == 0 ? pw_q : (which == 1 ? pw_kv : pw_kv + C_*C_);
        f16* Mo         = which == 0 ? Mq : (which == 1 ? Mk : Mv);
        __shared__ float wrow[C_];
        wrow[tid] = Wm[o*C_ + tid];
        __syncthreads();
        float acc = 0.f;
        #pragma unroll 8
        for (int j = 0; j < C_; ++j)
            acc = fmaf(wrow[j], P[j*C_ + tid], acc);
        Mo[o*C_ + tid] = (f16)acc;
    } else {
        int i = (blk - 576)*192 + tid;          // 24576 pad elements exactly
        int b = i / (C_*16);
        int rem = i % (C_*16);
        int c = rem / 16;
        int m = MM + (rem & 15);
        vt[((size_t)b*C_ + c)*VT_LD + m] = (f16)0.f;
    }
}

// ---------------------------------------------------------------------------
// Depthwise 3x3 + BN for both paths in one launch. fp32 compute, f16 out.
__device__ __forceinline__ void dwbn_one(
    const float* __restrict__ x, const float* __restrict__ dw,
    const float* __restrict__ gamma, const float* __restrict__ beta,
    const float* __restrict__ mean,  const float* __restrict__ var,
    f16* __restrict__ out, int OH, int OW, int stride, int idx)
{
    int c4 = idx % (C_/4);
    int sp = idx / (C_/4);
    int ox = sp % OW;
    int t2 = sp / OW;
    int oy = t2 % OH;
    int b  = t2 / OH;
    int c0 = c4*4;
    float4 acc = make_float4(0.f,0.f,0.f,0.f);
    int iy0 = oy*stride - 1;
    int ix0 = ox*stride - 1;
    #pragma unroll
    for (int ky = 0; ky < 3; ++ky) {
        int iy = iy0 + ky;
        if (iy < 0 || iy >= HH) continue;
        #pragma unroll
        for (int kx = 0; kx < 3; ++kx) {
            int ix = ix0 + kx;
            if (ix < 0 || ix >= WW) continue;
            float4 xv = *reinterpret_cast<const float4*>(
                x + ((size_t)b*NN + iy*WW + ix)*C_ + c0);
            int wi = ky*3 + kx;
            acc.x = fmaf(dw[(c0+0)*9 + wi], xv.x, acc.x);
            acc.y = fmaf(dw[(c0+1)*9 + wi], xv.y, acc.y);
            acc.z = fmaf(dw[(c0+2)*9 + wi], xv.z, acc.z);
            acc.w = fmaf(dw[(c0+3)*9 + wi], xv.w, acc.w);
        }
    }
    float i0 = gamma[c0+0]*__frsqrt_rn(var[c0+0] + 1e-5f);
    float i1 = gamma[c0+1]*__frsqrt_rn(var[c0+1] + 1e-5f);
    float i2 = gamma[c0+2]*__frsqrt_rn(var[c0+2] + 1e-5f);
    float i3 = gamma[c0+3]*__frsqrt_rn(var[c0+3] + 1e-5f);
    f16x4 r;
    r[0] = (f16)(acc.x*i0 + (beta[c0+0] - mean[c0+0]*i0));
    r[1] = (f16)(acc.y*i1 + (beta[c0+1] - mean[c0+1]*i1));
    r[2] = (f16)(acc.z*i2 + (beta[c0+2] - mean[c0+2]*i2));
    r[3] = (f16)(acc.w*i3 + (beta[c0+3] - mean[c0+3]*i3));
    *reinterpret_cast<f16x4*>(out + (size_t)idx*4) = r;
}

__global__ __launch_bounds__(256) void dwbn_both(
    const float* __restrict__ x,
    const float* __restrict__ dwq,  const float* __restrict__ gq,
    const float* __restrict__ bq_,  const float* __restrict__ mq,
    const float* __restrict__ vq,
    const float* __restrict__ dwkv, const float* __restrict__ gkv,
    const float* __restrict__ bkv,  const float* __restrict__ mkv,
    const float* __restrict__ vkv,
    f16* __restrict__ uq, f16* __restrict__ ukv)
{
    int idx = blockIdx.x*256 + threadIdx.x;
    const int totq = BB*NN*(C_/4);          // 1204224
    const int totk = BB*MM*(C_/4);          // 301056
    if (idx < totq) {
        dwbn_one(x, dwq, gq, bq_, mq, vq, uq, HH, WW, 1, idx);
    } else {
        int i2 = idx - totq;
        if (i2 < totk)
            dwbn_one(x, dwkv, gkv, bkv, mkv, vkv, ukv, 28, 28, 2, i2);
    }
}

// ---------------------------------------------------------------------------
// All projections, one launch. blocks 0..391: Q path (64 rows each).
// blocks 392..489: KV path — A-fragments loaded once, used for K and V.
__global__ __launch_bounds__(256) void proj_all(
    const f16* __restrict__ uq, const f16* __restrict__ ukv,
    const f16* __restrict__ Mq, const f16* __restrict__ Mk,
    const f16* __restrict__ Mv,
    const float* __restrict__ bq, const float* __restrict__ bk,
    const float* __restrict__ bv,
    f16* __restrict__ qb, f16* __restrict__ kb, f16* __restrict__ vt)
{
    int tid  = threadIdx.x;
    int w    = tid >> 6, l = tid & 63;
    int lrow = l & 15,  lgrp = l >> 4;
    int blk  = blockIdx.x;
    bool qpath = blk < QPB;
    const f16* U = qpath ? uq : ukv;
    int r0 = (qpath ? blk : blk - QPB)*64 + w*16;

    const f16* urow = U + (size_t)(r0 + lrow)*C_;
    f16x8 a[6];
    #pragma unroll
    for (int ch = 0; ch < 6; ++ch)
        a[ch] = *(const f16x8*)(urow + ch*32 + lgrp*8);

    if (qpath) {
        const float qscale = 0.14433756729740643f;   // 1/sqrt(48)
        for (int ct = 0; ct < 12; ++ct) {
            int o = ct*16 + lrow;
            const f16* mrow = Mq + (size_t)o*C_;
            f32x4 acc = {0.f,0.f,0.f,0.f};
            #pragma unroll
            for (int ch = 0; ch < 6; ++ch) {
                f16x8 bf = *(const f16x8*)(mrow + ch*32 + lgrp*8);
                acc = __builtin_amdgcn_mfma_f32_16x16x32_f16(a[ch], bf, acc, 0, 0, 0);
            }
            float bo = bq[o];
            #pragma unroll
            for (int i = 0; i < 4; ++i)
                qb[(size_t)(r0 + lgrp*4 + i)*C_ + o] = (f16)((acc[i] + bo)*qscale);
        }
    } else {
        for (int ct = 0; ct < 12; ++ct) {            // K projection
            int o = ct*16 + lrow;
            const f16* mrow = Mk + (size_t)o*C_;
            f32x4 acc = {0.f,0.f,0.f,0.f};
            #pragma unroll
            for (int ch = 0; ch < 6; ++ch) {
                f16x8 bf = *(const f16x8*)(mrow + ch*32 + lgrp*8);
                acc = __builtin_amdgcn_mfma_f32_16x16x32_f16(a[ch], bf, acc, 0, 0, 0);
            }
            float bo = bk[o];
            #pragma unroll
            for (int i = 0; i < 4; ++i)
                kb[(size_t)(r0 + lgrp*4 + i)*C_ + o] = (f16)(acc[i] + bo);
        }
        for (int ct = 0; ct < 12; ++ct) {            // V projection (transposed)
            int o = ct*16 + lrow;
            const f16* mrow = Mv + (size_t)o*C_;
            f32x4 acc = {0.f,0.f,0.f,0.f};
            #pragma unroll
            for (int ch = 0; ch < 6; ++ch) {
                f16x8 bf = *(const f16x8*)(mrow + ch*32 + lgrp*8);
                acc = __builtin_amdgcn_mfma_f32_16x16x32_f16(a[ch], bf, acc, 0, 0, 0);
            }
            float bo = bv[o];
            int rg = r0 + lgrp*4;
            int b  = rg / MM, m = rg % MM;            // 784 % 16 == 0, no straddle
            #pragma unroll
            for (int i = 0; i < 4; ++i)
                vt[((size_t)b*C_ + o)*VT_LD + m + i] = (f16)(acc[i] + bo);
        }
    }
}

// ---------------------------------------------------------------------------
// Flash attention with MFMA. 2 independent waves/block, 16 q-rows per wave,
// KV tile = 112 keys (784 = 7*112 exact). NO barriers: each wave owns its own
// pL slice; in-wave DS ordering is guaranteed by the hardware/compiler.
__global__ __launch_bounds__(128) void attn_mfma(
    const f16* __restrict__ qb, const f16* __restrict__ kb,
    const f16* __restrict__ vt, float* __restrict__ out)
{
    __shared__ __align__(16) f16 pL[2][16*128];   // per-wave P, XOR-swizzled

    int tid  = threadIdx.x;
    int w    = tid >> 6, l = tid & 63;
    int lrow = l & 15,  lgrp = l >> 4;
    int bid  = blockIdx.x;
    int qt   = bid % (NN/32);
    int h    = (bid/(NN/32)) & 3;
    int b    = bid / ((NN/32)*NHEAD);
    int n0   = qt*32 + w*16;
    f16* pw  = &pL[w][0];

    // zero pad columns 112..127 once (this wave's slice only)
    {
        int q = lrow;
        int e = (q*128 + 112 + lgrp*4) ^ ((q & 7) << 3);
        *(f16x4*)(pw + e) = (f16x4){0,0,0,0};
    }

    // Q fragments in registers for the whole kernel; d>=48 pad = 0
    const f16* qrow = qb + ((size_t)b*NN + n0 + lrow)*C_ + h*HD;
    f16x8 qf0 = *(const f16x8*)(qrow + lgrp*8);
    f16x8 qf1 = (f16x8){0,0,0,0,0,0,0,0};
    if (lgrp < 2) qf1 = *(const f16x8*)(qrow + 32 + lgrp*8);

    float mrun[4], lrun[4];
    #pragma unroll
    for (int r = 0; r < 4; ++r) { mrun[r] = -1e30f; lrun[r] = 0.f; }
    f32x4 o0 = {0.f,0.f,0.f,0.f}, o1 = o0, o2 = o0;

    for (int t = 0; t < 7; ++t) {
        int m0 = t*112;

        // ---- QK^T: S tile 16 x 112, K frags from global (L1/L2-hot)
        f32x4 s[7];
        #pragma unroll
        for (int kt = 0; kt < 7; ++kt) {
            const f16* krow = kb + ((size_t)b*MM + m0 + kt*16 + lrow)*C_ + h*HD;
            f16x8 kf0 = *(const f16x8*)(krow + lgrp*8);
            f16x8 kf1 = *(const f16x8*)(krow + 32 + lgrp*8); // d>=48 junk * 0 = 0
            f32x4 acc = {0.f,0.f,0.f,0.f};
            __builtin_amdgcn_s_setprio(1);
            acc = __builtin_amdgcn_mfma_f32_16x16x32_f16(qf0, kf0, acc, 0, 0, 0);
            acc = __builtin_amdgcn_mfma_f32_16x16x32_f16(qf1, kf1, acc, 0, 0, 0);
            __builtin_amdgcn_s_setprio(0);
            s[kt] = acc;
        }

        // ---- online softmax (fp32). D row = lgrp*4+r, col = kt*16+lrow.
        float corr[4];
        #pragma unroll
        for (int r = 0; r < 4; ++r) {
            float tmax = s[0][r];
            #pragma unroll
            for (int kt = 1; kt < 7; ++kt) tmax = fmaxf(tmax, s[kt][r]);
            tmax = fmaxf(tmax, __shfl_xor(tmax, 1));
            tmax = fmaxf(tmax, __shfl_xor(tmax, 2));
            tmax = fmaxf(tmax, __shfl_xor(tmax, 4));
            tmax = fmaxf(tmax, __shfl_xor(tmax, 8));
            float mnew = fmaxf(mrun[r], tmax);
            corr[r] = __expf(mrun[r] - mnew);
            mrun[r] = mnew;
            float psum = 0.f;
            #pragma unroll
            for (int kt = 0; kt < 7; ++kt) {
                float p = __expf(s[kt][r] - mnew);
                s[kt][r] = p;
                psum += p;
            }
            psum += __shfl_xor(psum, 1);
            psum += __shfl_xor(psum, 2);
            psum += __shfl_xor(psum, 4);
            psum += __shfl_xor(psum, 8);
            lrun[r] = lrun[r]*corr[r] + psum;
        }

        // ---- write P (f16) to this wave's swizzled LDS slice
        #pragma unroll
        for (int r = 0; r < 4; ++r) {
            int q = lgrp*4 + r;
            #pragma unroll
            for (int kt = 0; kt < 7; ++kt) {
                int e = (q*128 + kt*16 + lrow) ^ ((q & 7) << 3);
                pw[e] = (f16)s[kt][r];
            }
        }

        // ---- rescale O accumulators
        #pragma unroll
        for (int r = 0; r < 4; ++r) {
            o0[r] *= corr[r]; o1[r] *= corr[r]; o2[r] *= corr[r];
        }

        // ---- PV: O(16x48) += P(16x128) * V(128x48), V^T frags from global
        f16x8 pa[4];
        #pragma unroll
        for (int kc = 0; kc < 4; ++kc) {
            int e = (lrow*128 + kc*32 + lgrp*8) ^ ((lrow & 7) << 3);
            pa[kc] = *(const f16x8*)(pw + e);
        }
        const f16* vbase = vt + ((size_t)b*C_ + h*HD + lrow)*VT_LD + m0;
        #pragma unroll
        for (int kc = 0; kc < 4; ++kc) {
            f16x8 v0 = *(const f16x8*)(vbase + kc*32 + lgrp*8);
            f16x8 v1 = *(const f16x8*)(vbase + 16*VT_LD + kc*32 + lgrp*8);
            f16x8 v2 = *(const f16x8*)(vbase + 32*VT_LD + kc*32 + lgrp*8);
            __builtin_amdgcn_s_setprio(1);
            o0 = __builtin_amdgcn_mfma_f32_16x16x32_f16(pa[kc], v0, o0, 0, 0, 0);
            o1 = __builtin_amdgcn_mfma_f32_16x16x32_f16(pa[kc], v1, o1, 0, 0, 0);
            o2 = __builtin_amdgcn_mfma_f32_16x16x32_f16(pa[kc], v2, o2, 0, 0, 0);
            __builtin_amdgcn_s_setprio(0);
        }
    }

    // ---- epilogue: divide by l, store fp32
    #pragma unroll
    for (int r = 0; r < 4; ++r) {
        float inv = 1.f / lrun[r];
        size_t obase = ((size_t)b*NN + n0 + lgrp*4 + r)*C_ + h*HD + lrow;
        out[obase]      = o0[r]*inv;
        out[obase + 16] = o1[r]*inv;
        out[obase + 32] = o2[r]*inv;
    }
}

// ---------------------------------------------------------------------------
extern "C" void kernel_launch(void* const* d_in, const int* in_sizes, int n_in,
                              void* d_out, int out_size, void* d_ws, size_t ws_size,
                              hipStream_t stream)
{
    const float* x     = (const float*)d_in[0];
    const float* dw_q  = (const float*)d_in[3];
    const float* bnqg  = (const float*)d_in[4];
    const float* bnqb  = (const float*)d_in[5];
    const float* bnqm  = (const float*)d_in[6];
    const float* bnqv  = (const float*)d_in[7];
    const float* pw_q  = (const float*)d_in[8];
    const float* dw_kv = (const float*)d_in[9];
    const float* bnkg  = (const float*)d_in[10];
    const float* bnkb  = (const float*)d_in[11];
    const float* bnkm  = (const float*)d_in[12];
    const float* bnkvv = (const float*)d_in[13];
    const float* pw_kv = (const float*)d_in[14];
    const float* Wq    = (const float*)d_in[15];
    const float* bq    = (const float*)d_in[16];
    const float* Wk    = (const float*)d_in[17];
    const float* bk    = (const float*)d_in[18];
    const float* Wv    = (const float*)d_in[19];
    const float* bv    = (const float*)d_in[20];
    float* out = (float*)d_out;

    f16* p   = (f16*)d_ws;
    f16* Mq16  = p;  p += C_*C_;
    f16* Mk16  = p;  p += C_*C_;
    f16* Mv16  = p;  p += C_*C_;
    f16* uq16  = p;  p += (size_t)BB*NN*C_;
    f16* ukv16 = p;  p += (size_t)BB*MM*C_;
    f16* qb16  = p;  p += (size_t)BB*NN*C_ + 256;   // pad: frag tail reads
    f16* kb16  = p;  p += (size_t)BB*MM*C_ + 256;   // pad: frag tail reads
    f16* vt16  = p;  p += (size_t)BB*C_*VT_LD;

    setup_kernel<<<704, 192, 0, stream>>>(
        Wq, Wk, Wv, pw_q, pw_kv, Mq16, Mk16, Mv16, vt16);

    dwbn_both<<<5880, 256, 0, stream>>>(
        x, dw_q, bnqg, bnqb, bnqm, bnqv,
        dw_kv, bnkg, bnkb, bnkm, bnkvv, uq16, ukv16);

    proj_all<<<QPB + KVPB, 256, 0, stream>>>(
        uq16, ukv16, Mq16, Mk16, Mv16, bq, bk, bv, qb16, kb16, vt16);

    attn_mfma<<<BB*NHEAD*(NN/32), 128, 0, stream>>>(qb16, kb16, vt16, out);
}